// Round 12
// baseline (14456.760 us; speedup 1.0000x reference)
//
#include <hip/hip_runtime.h>
#include <hip/hip_bf16.h>
#include <cstddef>

#define kT 256
#define kB 128
#define kINP 512
#define kH 512
#define kK 32
#define kR 64
#define kNEG (-1e30f)

// ---------------------------------------------------------------------------
// agent-scope (device-coherent, cache-bypassing) accessors, RELAXED order.
// Protocol (validated r3-r5/r9/r10): publish data via ag_store; set_flag's
// __syncthreads drains vmcnt per wave before tid0 stores the flag; waiters
// spin the flag (tid<3), barrier, then ag_load the data.
// ---------------------------------------------------------------------------
__device__ __forceinline__ void ag_store(float* p, float v) {
    __hip_atomic_store(p, v, __ATOMIC_RELAXED, __HIP_MEMORY_SCOPE_AGENT);
}
__device__ __forceinline__ float ag_load(const float* p) {
    return __hip_atomic_load(p, __ATOMIC_RELAXED, __HIP_MEMORY_SCOPE_AGENT);
}

// fast tanh for attention scores (error ~1e-7, stable at +-inf)
__device__ __forceinline__ float ftanh(float x)
{
    float e = __expf(2.0f * x);
    return 1.0f - 2.0f * __builtin_amdgcn_rcpf(e + 1.0f);
}

// ---------------------------------------------------------------------------
// XU = x @ Uw + Ub.  64x64 tile, BK=32, 256 threads, 4x4 acc/thread.
// ---------------------------------------------------------------------------
__global__ __launch_bounds__(256) void gemm_xu(
    const float* __restrict__ A, const float* __restrict__ W,
    const float* __restrict__ bias, float* __restrict__ C)
{
    __shared__ float At[32][68];   // A tile transposed: At[k][m]
    __shared__ float Ws[32][68];
    const int tid = threadIdx.x;
    const int n0 = blockIdx.x * 64;
    const int m0 = blockIdx.y * 64;
    const int tx = tid & 15, ty = tid >> 4;
    const int arow = tid >> 3, ak = (tid & 7) << 2;
    const int wrow = tid >> 4, wc = (tid & 15) << 2;

    float acc[4][4] = {};

    for (int k0 = 0; k0 < kINP; k0 += 32) {
        float4 a0 = *reinterpret_cast<const float4*>(&A[(size_t)(m0 + arow) * kINP + k0 + ak]);
        float4 a1 = *reinterpret_cast<const float4*>(&A[(size_t)(m0 + 32 + arow) * kINP + k0 + ak]);
        float4 w0 = *reinterpret_cast<const float4*>(&W[(size_t)(k0 + wrow) * kH + n0 + wc]);
        float4 w1 = *reinterpret_cast<const float4*>(&W[(size_t)(k0 + wrow + 16) * kH + n0 + wc]);
        __syncthreads();
        At[ak + 0][arow] = a0.x; At[ak + 1][arow] = a0.y;
        At[ak + 2][arow] = a0.z; At[ak + 3][arow] = a0.w;
        At[ak + 0][32 + arow] = a1.x; At[ak + 1][32 + arow] = a1.y;
        At[ak + 2][32 + arow] = a1.z; At[ak + 3][32 + arow] = a1.w;
        *reinterpret_cast<float4*>(&Ws[wrow][wc]) = w0;
        *reinterpret_cast<float4*>(&Ws[wrow + 16][wc]) = w1;
        __syncthreads();
#pragma unroll
        for (int kk = 0; kk < 32; ++kk) {
            float4 a4 = *reinterpret_cast<float4*>(&At[kk][ty * 4]);
            float4 w4 = *reinterpret_cast<float4*>(&Ws[kk][tx * 4]);
            float a_[4] = {a4.x, a4.y, a4.z, a4.w};
            float w_[4] = {w4.x, w4.y, w4.z, w4.w};
#pragma unroll
            for (int r = 0; r < 4; ++r)
#pragma unroll
                for (int c = 0; c < 4; ++c)
                    acc[r][c] += a_[r] * w_[c];
        }
    }

#pragma unroll
    for (int r = 0; r < 4; ++r) {
        int m = m0 + ty * 4 + r;
#pragma unroll
        for (int c = 0; c < 4; ++c) {
            int n = n0 + tx * 4 + c;
            C[(size_t)m * kH + n] = acc[r][c] + bias[n];
        }
    }
}

__global__ __launch_bounds__(256) void init_flags_k(int* __restrict__ flags)
{
    int i = blockIdx.x * 256 + threadIdx.x;
    if (i < 64 * 3 * 4) flags[i] = 0;
}

// matvec inner step: 2 k-rows per wave-iteration (lanes 0-31 row k, 32-63
// row k+1), dual-batch accumulate.  k(i) = i*32 + w*2 + half32.
#define MV_STEP(Wmat, xs, i, A0, A1) { \
    int k_ = (i)*32 + (w << 1) + half32; \
    const float4 wt_ = *reinterpret_cast<const float4*>(&Wmat[(size_t)k_ * kH + C0 + c4]); \
    float s0_ = xs[0][k_], s1_ = xs[1][k_]; \
    A0.x += s0_*wt_.x; A0.y += s0_*wt_.y; A0.z += s0_*wt_.z; A0.w += s0_*wt_.w; \
    A1.x += s1_*wt_.x; A1.y += s1_*wt_.y; A1.z += s1_*wt_.z; A1.w += s1_*wt_.w; }

// combine the two k-parity half-waves, store per-batch partials to part[]
#define MV_FINISH(A0, A1) { \
    A0.x += __shfl_xor(A0.x, 32); A0.y += __shfl_xor(A0.y, 32); \
    A0.z += __shfl_xor(A0.z, 32); A0.w += __shfl_xor(A0.w, 32); \
    A1.x += __shfl_xor(A1.x, 32); A1.y += __shfl_xor(A1.y, 32); \
    A1.z += __shfl_xor(A1.z, 32); A1.w += __shfl_xor(A1.w, 32); \
    if (lane < 32) { \
        *reinterpret_cast<float4*>(&part[(w*2 + 0)*128 + c4]) = A0; \
        *reinterpret_cast<float4*>(&part[(w*2 + 1)*128 + c4]) = A1; } }

// ---------------------------------------------------------------------------
// Quad-split persistent recurrence: 256 blocks = 64 groups x 4. Group g
// handles batches (2g, 2g+1); block q owns columns [q*128, q*128+128).
// Weight traffic halves vs the pair version (each float4 feeds 2 batches).
// Phase order is exactly r10's: A(Uaw) -> es exchange -> softmax -> ct/st ->
// evict -> B(Vw) -> fC flag -> va(Vaw) in partner shadow.
// ---------------------------------------------------------------------------
__global__ __launch_bounds__(1024) void rnn_quad(
    const float* __restrict__ Vw, const float* __restrict__ Vaw,
    const float* __restrict__ Uaw, const float* __restrict__ vvec,
    const float* __restrict__ XU, float* __restrict__ lngU,
    float* __restrict__ hs, float* __restrict__ esx,
    float* __restrict__ stx, int* __restrict__ flags)
{
    extern __shared__ float dyn[];
    float* shortH = dyn;                  // [2][32][128]
    float* shortU = dyn + 8192;           // [2][32][128]
    float* longH  = dyn + 16384;          // [2][64][128]
    float* part   = dyn + 32768;          // [4096] matvec [16][2][128] / ct [16][128]

    const int bid = blockIdx.x;
    const int g = bid >> 2, q = bid & 3;
    const int bA = g << 1;                // first batch of this group's pair
    const int C0 = q << 7;                // own column base (128 cols)
    const int tid = threadIdx.x;
    const int w = tid >> 6;               // wave 0..15
    const int lane = tid & 63;
    const int half32 = lane >> 5;         // k-parity in the 2-row trick
    const int c4 = (lane & 31) << 2;      // col 0..124 step 4
    const int c2 = lane << 1;             // col 0..126 step 2
    const int i0 = q << 2;                // own-quarter iterations [i0, i0+4)

    __shared__ __align__(16) float h_sh[2][512];
    __shared__ __align__(16) float st_sh[2][512];
    __shared__ __align__(16) float va_sh[2][128];
    __shared__ __align__(16) float v_sh[128];
    __shared__ float es_own[2][96], es_sh[2][96], w_sh[2][96];
    __shared__ int   rowm[2][96];
    __shared__ float lsc_sh[2][64];       // circular window by (row & 63)
    __shared__ float buck_sh[2][64];
    __shared__ int   lidx_sh[2][64];
    __shared__ int   fcnt_sh[2], evict_pos[2];
    __shared__ float red0[2], red1[2];

    float* lngU_b = lngU + (size_t)bid * 2 * kR * 128;
    const int fbase = g * 12;             // flags[(g*3 + phase)*4 + q]

    auto wait3 = [&](int phase, int target) {
        if (tid < 3) {
            int p = tid + (tid >= q ? 1 : 0);
            int* f = &flags[fbase + phase * 4 + p];
            while (__hip_atomic_load(f, __ATOMIC_RELAXED, __HIP_MEMORY_SCOPE_AGENT) < target)
                __builtin_amdgcn_s_sleep(1);
        }
        __syncthreads();
    };
    auto set_flag = [&](int phase, int val) {
        __syncthreads();   // drains vmcnt: prior agent stores at coherence point
        if (tid == 0)
            __hip_atomic_store(&flags[fbase + phase * 4 + q], val,
                               __ATOMIC_RELAXED, __HIP_MEMORY_SCOPE_AGENT);
    };

    // ---- prologue (t = 0): st_0 = pre = XU[0]; h_0 = tanh(pre)
    if (tid < 128) v_sh[tid] = vvec[C0 + tid];
    if (tid < 128) {
        int bb = tid >> 6, s = tid & 63;
        lsc_sh[bb][s] = 0.0f; buck_sh[bb][s] = 0.0f; lidx_sh[bb][s] = -1;
    }
    if (tid < 2) fcnt_sh[tid] = 0;
    {
        int bb = tid >> 9, col = tid & 511;
        st_sh[bb][col] = XU[(size_t)(bA + bb) * kH + col];
    }
    __syncthreads();
    if (tid < 256) {
        int bb = tid >> 7, col = tid & 127;
        float h0 = tanhf(st_sh[bb][C0 + col]);
        h_sh[bb][C0 + col] = h0;
        shortH[(bb * 32 + 0) * 128 + col] = h0;            // slot 0 <- h_0
        ag_store(&hs[(size_t)(bA + bb) * kH + C0 + col], h0);
    }
    set_flag(0, 1);
    // va_0 = st_0 @ Vaw[:, C]  (full k, st_0 from XU)
    {
        float4 a0 = {0,0,0,0}, a1 = {0,0,0,0};
#pragma unroll
        for (int i = 0; i < 16; ++i) MV_STEP(Vaw, st_sh, i, a0, a1);
        MV_FINISH(a0, a1);
        __syncthreads();
        if (tid < 256) {
            int bb = tid >> 7, col = tid & 127;
            float s = 0.0f;
#pragma unroll
            for (int j = 0; j < 16; ++j) s += part[(j * 2 + bb) * 128 + col];
            va_sh[bb][col] = s;
        }
        __syncthreads();
    }

    for (int t = 1; t < kT; ++t) {
        float xu_reg = 0.0f;
        if (tid < 256) {
            int bb = tid >> 7, col = tid & 127;
            xu_reg = XU[((size_t)t * kB + (bA + bb)) * kH + C0 + col];
        }

        // ---- A matvec (Uaw): own-quarter k pre-wait
        float4 aU0 = {0,0,0,0}, aU1 = {0,0,0,0};
#pragma unroll
        for (int i = 0; i < 4; ++i) MV_STEP(Uaw, h_sh, i0 + i, aU0, aU1);
        if (tid < 192) {
            int bb = (tid >= 96), m = tid - bb * 96;
            int row;
            if (m < kK) { int md = (t + 31 - m) & 31; row = t - 1 - md; }
            else row = lidx_sh[bb][m - kK];
            rowm[bb][m] = row;
        }
        wait3(0, t);                                       // fC: h_{t-1} ready
        if (tid < 768) {                                   // assemble partner quarters
            int bb = tid / 384, j = tid - bb * 384;
            int pq = j >> 7, col = j & 127;
            int qq = pq + (pq >= q ? 1 : 0);
            h_sh[bb][qq * 128 + col] =
                ag_load(&hs[((size_t)(t - 1) * kB + (bA + bb)) * kH + qq * 128 + col]);
        }
        __syncthreads();
        for (int i = 0; i < i0; ++i) MV_STEP(Uaw, h_sh, i, aU0, aU1);
        for (int i = i0 + 4; i < 16; ++i) MV_STEP(Uaw, h_sh, i, aU0, aU1);
        MV_FINISH(aU0, aU1);
        __syncthreads();
        if (tid < 256) {
            int bb = tid >> 7, col = tid & 127;
            float u = 0.0f;
#pragma unroll
            for (int j = 0; j < 16; ++j) u += part[(j * 2 + bb) * 128 + col];
            shortU[(bb * 32 + ((t - 1) & 31)) * 128 + col] = u;  // slot (t-1)%32
        }
        __syncthreads();

        // ---- es partials over own 128 cols: wave w -> batch w>>3, rows (w&7)+8r
        {
            int bb = w >> 3, wr = w & 7;
            float2 vav = *reinterpret_cast<const float2*>(&va_sh[bb][c2]);
            float2 vvv = *reinterpret_cast<const float2*>(&v_sh[c2]);
#pragma unroll
            for (int r = 0; r < 12; ++r) {
                int m = wr + (r << 3);
                int row = rowm[bb][m];
                float p = 0.0f;
                if (row >= 0) {
                    const float* up = (m < kK) ? &shortU[(bb * 32 + m) * 128]
                                               : &lngU_b[(size_t)(bb * kR + (m - kK)) * 128];
                    float2 uu = *reinterpret_cast<const float2*>(&up[c2]);
                    p = vvv.x * ftanh(vav.x + uu.x) + vvv.y * ftanh(vav.y + uu.y);
                }
#pragma unroll
                for (int off = 32; off; off >>= 1) p += __shfl_down(p, off);
                if (lane == 0) es_own[bb][m] = p;
            }
        }
        __syncthreads();
        if (tid < 192) {
            int bb = (tid >= 96), m = tid - bb * 96;
            ag_store(&esx[(size_t)bid * 192 + bb * 96 + m], es_own[bb][m]);
        }
        set_flag(1, t);                                    // fB
        wait3(1, t);
        if (tid < 192) {
            int bb = (tid >= 96), m = tid - bb * 96;
            float e = kNEG;
            if (rowm[bb][m] >= 0) {
                e = 0.0f;
#pragma unroll
                for (int p = 0; p < 4; ++p)                // fixed q-order: identical in all blocks
                    e += ag_load(&esx[(size_t)(g * 4 + p) * 192 + bb * 96 + m]);
            }
            es_sh[bb][m] = e;
        }
        __syncthreads();

        // ---- softmax over 96, per batch (waves 0/1), r10's exact sequence
        if (w < 2) {
            float a = es_sh[w][lane];
            float b2 = (lane < 32) ? es_sh[w][64 + lane] : kNEG;
            float mx = fmaxf(a, b2);
#pragma unroll
            for (int off = 32; off; off >>= 1) mx = fmaxf(mx, __shfl_xor(mx, off));
            if (lane == 0) red0[w] = mx;
        }
        __syncthreads();
        if (tid < 192) {
            int bb = (tid >= 96), m = tid - bb * 96;
            w_sh[bb][m] = __expf(es_sh[bb][m] - red0[bb]);
        }
        __syncthreads();
        if (w < 2) {
            float a = w_sh[w][lane] + ((lane < 32) ? w_sh[w][64 + lane] : 0.0f);
#pragma unroll
            for (int off = 32; off; off >>= 1) a += __shfl_xor(a, off);
            if (lane == 0) red1[w] = 1.0f / a;
        }
        __syncthreads();

        // ---- ct partials (shortH / longH, both LDS)
        {
            int bb = w >> 3, wr = w & 7;
            float2 acc = {0.0f, 0.0f};
#pragma unroll
            for (int r = 0; r < 12; ++r) {
                int m = wr + (r << 3);
                int row = rowm[bb][m];
                if (row >= 0) {
                    const float* hp = (m < kK) ? &shortH[(bb * 32 + m) * 128]
                                               : &longH[(bb * kR + (m - kK)) * 128];
                    float2 hv = *reinterpret_cast<const float2*>(&hp[c2]);
                    float wq = w_sh[bb][m];
                    acc.x += wq * hv.x; acc.y += wq * hv.y;
                }
            }
            *reinterpret_cast<float2*>(&part[w * 128 + c2]) = acc;
        }
        __syncthreads();
        if (tid < 256) {
            int bb = tid >> 7, col = tid & 127;
            float ct = 0.0f;
#pragma unroll
            for (int j = 0; j < 8; ++j) ct += part[(bb * 8 + j) * 128 + col];
            float stv = 0.5f * (h_sh[bb][C0 + col] + ct * red1[bb]);
            st_sh[bb][C0 + col] = stv;
            ag_store(&stx[(size_t)(bA + bb) * kH + C0 + col], stv);
        }
        set_flag(2, t);                                    // fS

        // ---- long_scores accumulate (wave 0) + eviction (tid 0/1, replicated)
        if (tid < 64) {
            int bb = tid >> 5, s = tid & 31;
            int row = rowm[bb][s];
            if (row >= 0) lsc_sh[bb][row & 63] += w_sh[bb][s] * red1[bb];
        }
        __syncthreads();
        if (tid < 2) {
            int bb = tid, ep = -1;
            if (t >= kK) {
                float score = lsc_sh[bb][(t - kK) & 63];
                lsc_sh[bb][(t - kK) & 63] = 0.0f;          // retire slot (single read done)
                int fc = fcnt_sh[bb];
                bool nf = fc < kR;
                float mn = buck_sh[bb][0]; int mp = 0;
                for (int r2 = 1; r2 < kR; ++r2) {
                    float bv = buck_sh[bb][r2];
                    if (bv < mn) { mn = bv; mp = r2; }
                }
                if (nf || score > mn) {
                    ep = nf ? fc : mp;
                    lidx_sh[bb][ep] = t - kK;
                    buck_sh[bb][ep] = score;
                    if (nf) fcnt_sh[bb] = fc + 1;
                }
            }
            evict_pos[bb] = ep;
        }
        __syncthreads();
        if (tid < 512) {      // evicted candidate = slot t%32, copy before overwrite
            int bb = tid >> 8, j = tid & 255;
            int ep = evict_pos[bb];
            if (ep >= 0) {
                int slot = t & 31;
                if (j < 128)
                    longH[(bb * kR + ep) * 128 + j] = shortH[(bb * 32 + slot) * 128 + j];
                else {
                    int col = j - 128;
                    lngU_b[(size_t)(bb * kR + ep) * 128 + col] =
                        shortU[(bb * 32 + slot) * 128 + col];
                }
            }
        }

        // ---- B matvec (Vw): h_pre = st @ Vw[:, C] + XU[t]; own-quarter pre-wait
        float4 aW0 = {0,0,0,0}, aW1 = {0,0,0,0};
#pragma unroll
        for (int i = 0; i < 4; ++i) MV_STEP(Vw, st_sh, i0 + i, aW0, aW1);
        wait3(2, t);                                       // fS: partner st ready
        if (tid < 768) {
            int bb = tid / 384, j = tid - bb * 384;
            int pq = j >> 7, col = j & 127;
            int qq = pq + (pq >= q ? 1 : 0);
            st_sh[bb][qq * 128 + col] =
                ag_load(&stx[(size_t)(bA + bb) * kH + qq * 128 + col]);
        }
        __syncthreads();
        for (int i = 0; i < i0; ++i) MV_STEP(Vw, st_sh, i, aW0, aW1);
        for (int i = i0 + 4; i < 16; ++i) MV_STEP(Vw, st_sh, i, aW0, aW1);
        MV_FINISH(aW0, aW1);
        __syncthreads();
        if (tid < 256) {
            int bb = tid >> 7, col = tid & 127;
            float hpre = xu_reg;
#pragma unroll
            for (int j = 0; j < 16; ++j) hpre += part[(j * 2 + bb) * 128 + col];
            float hv = tanhf(hpre);
            h_sh[bb][C0 + col] = hv;
            shortH[(bb * 32 + (t & 31)) * 128 + col] = hv;  // slot t%32 <- h_t
            ag_store(&hs[((size_t)t * kB + (bA + bb)) * kH + C0 + col], hv);
        }
        set_flag(0, t + 1);   // unblock partners' next A-phase early

        // ---- va' = st @ Vaw[:, C]  (full k; runs in partner-wait shadow, r10-style)
        {
            float4 aV0 = {0,0,0,0}, aV1 = {0,0,0,0};
#pragma unroll
            for (int i = 0; i < 16; ++i) MV_STEP(Vaw, st_sh, i, aV0, aV1);
            MV_FINISH(aV0, aV1);
            __syncthreads();
            if (tid < 256) {
                int bb = tid >> 7, col = tid & 127;
                float s = 0.0f;
#pragma unroll
                for (int j = 0; j < 16; ++j) s += part[(j * 2 + bb) * 128 + col];
                va_sh[bb][col] = s;
            }
            __syncthreads();
        }
    }
}

// ---------------------------------------------------------------------------
extern "C" void kernel_launch(void* const* d_in, const int* in_sizes, int n_in,
                              void* d_out, int out_size, void* d_ws, size_t ws_size,
                              hipStream_t stream)
{
    const float* x   = (const float*)d_in[0];
    const float* Uw  = (const float*)d_in[1];
    const float* Ub  = (const float*)d_in[2];
    const float* Vw  = (const float*)d_in[3];
    const float* Uaw = (const float*)d_in[4];
    const float* Vaw = (const float*)d_in[5];
    const float* vv  = (const float*)d_in[6];
    float* hs = (float*)d_out;

    float* ws = (float*)d_ws;
    const size_t TBH = (size_t)kT * kB * kH;
    float* XU   = ws;                               // T*B*H
    float* lngU = XU + TBH;                         // 256 blocks * 2*64*128
    float* esx  = lngU + (size_t)256 * 2 * kR * 128;
    float* stx  = esx + (size_t)256 * 192;          // B*H
    int*   flags = (int*)(stx + (size_t)kB * kH);   // 64*3*4

    // dynamic LDS: shortH(32K)+shortU(32K)+longH(64K)+part(16K) = 144 KiB
    const int dyn_bytes = (8192 + 8192 + 16384 + 4096) * 4;
    hipFuncSetAttribute(reinterpret_cast<const void*>(rnn_quad),
                        hipFuncAttributeMaxDynamicSharedMemorySize, dyn_bytes);

    init_flags_k<<<3, 256, 0, stream>>>(flags);

    // XU = x @ Uw + Ub
    gemm_xu<<<dim3(kH / 64, (kT * kB) / 64), 256, 0, stream>>>(x, Uw, Ub, XU);

    // quad-split recurrence: 64 groups x 4 blocks, 1024 threads each
    rnn_quad<<<256, 1024, dyn_bytes, stream>>>(
        Vw, Vaw, Uaw, vv, XU, lngU, hs, esx, stx, flags);
}